// Round 4
// baseline (6211.818 us; speedup 1.0000x reference)
//
#include <hip/hip_runtime.h>

#define BN_EPS 1e-5f

static inline size_t align_up(size_t x, size_t a) { return (x + a - 1) & ~(a - 1); }

// ---------------- histogram: float deg (sum ew) + int count per dst ----------------

__global__ void hist_kernel(const int* __restrict__ dst, const float* __restrict__ ew,
                            float* __restrict__ deg, int* __restrict__ cntc, int E) {
    int e = blockIdx.x * blockDim.x + threadIdx.x;
    if (e < E) {
        int d = dst[e];
        atomicAdd(&deg[d], ew[e]);
        atomicAdd(&cntc[d], 1);
    }
}

__global__ void dinv_kernel(float* deg, int N) {
    int i = blockIdx.x * blockDim.x + threadIdx.x;
    if (i < N) deg[i] = rsqrtf(deg[i] + 1.0f);   // +1 = self-loop weight
}

// ---------------- exclusive scan (3-phase) over cntc[N] -> rowptr/cursor ----------------

__global__ void scan1_kernel(const int* __restrict__ cnt, int* __restrict__ excl,
                             int* __restrict__ bsum, int N) {
    __shared__ int lds[256];
    int base = blockIdx.x * 1024;
    int t = threadIdx.x;
    int v[4]; int s = 0;
    #pragma unroll
    for (int j = 0; j < 4; ++j) {
        int idx = base + t * 4 + j;
        v[j] = (idx < N) ? cnt[idx] : 0;
        s += v[j];
    }
    lds[t] = s;
    __syncthreads();
    for (int off = 1; off < 256; off <<= 1) {
        int x = (t >= off) ? lds[t - off] : 0;
        __syncthreads();
        lds[t] += x;
        __syncthreads();
    }
    int run = lds[t] - s;
    #pragma unroll
    for (int j = 0; j < 4; ++j) {
        int idx = base + t * 4 + j;
        if (idx < N) excl[idx] = run;
        run += v[j];
    }
    if (t == 255) bsum[blockIdx.x] = lds[255];
}

__global__ void scan2_kernel(int* __restrict__ bsum, int nb) {
    __shared__ int lds[256];
    int t = threadIdx.x;
    int v = (t < nb) ? bsum[t] : 0;
    lds[t] = v;
    __syncthreads();
    for (int off = 1; off < 256; off <<= 1) {
        int x = (t >= off) ? lds[t - off] : 0;
        __syncthreads();
        lds[t] += x;
        __syncthreads();
    }
    if (t < nb) bsum[t] = lds[t] - v;
}

__global__ void scan3_kernel(const int* __restrict__ excl, const int* __restrict__ bsum,
                             int* __restrict__ rowptr, int* __restrict__ cursor, int N, int E) {
    int idx = blockIdx.x * blockDim.x + threadIdx.x;
    if (idx < N) {
        int v = excl[idx] + bsum[idx >> 10];
        rowptr[idx] = v;
        cursor[idx] = v;
    }
    if (idx == 0) rowptr[N] = E;
}

// ---------------- bucket edges by dst: edges[pos] = (src, norm) ----------------

__global__ void bucket_kernel(const int* __restrict__ src, const int* __restrict__ dst,
                              const float* __restrict__ ew, const float* __restrict__ dinv,
                              int* __restrict__ cursor, int2* __restrict__ edges, int E) {
    int e = blockIdx.x * blockDim.x + threadIdx.x;
    if (e >= E) return;
    int s = src[e], d = dst[e];
    float nrm = dinv[s] * ew[e] * dinv[d];
    int pos = atomicAdd(&cursor[d], 1);
    edges[pos] = make_int2(s, __float_as_int(nrm));
}

// ---------------- fp32 GEMM: Y[N x 128] = X[N x K] @ W[K x 128] ----------------
// 64 rows/block, 256 threads. Thread (cg=tid&15, r=tid>>4) computes rows
// {r, r+16, r+32, r+48} x cols {cg*4..+3, 64+cg*4..+3}.
// Bank layout: W reads at cg*4 / 64+cg*4 -> 16 addrs covering all 32 banks 2-way (free).
// sX row stride K+4 -> per-instruction row addrs on distinct banks.
// W staged in 32-k chunks (16 KB) with register prefetch; sX staged once.

template<int K>
__launch_bounds__(256)
__global__ void gemm_kernel(const float* __restrict__ X, const float* __restrict__ W,
                            float* __restrict__ Y, int N) {
    constexpr int KP = K + 4;          // padded sX row stride (words); 132%32=4, 104%32=8
    constexpr int K4 = K / 4;
    constexpr int NC = (K + 31) / 32;  // W chunks
    __shared__ float sX[64 * KP];
    __shared__ float sW[32 * 128];

    int row0 = blockIdx.x * 64;
    int tid = threadIdx.x;

    // stage X tile: 64 rows x K floats (coalesced float4)
    for (int i = tid; i < 64 * K4; i += 256) {
        int rr = i / K4, c4 = i - rr * K4;
        int row = row0 + rr;
        float4 v = make_float4(0.f, 0.f, 0.f, 0.f);
        if (row < N) v = ((const float4*)&X[(size_t)row * K])[c4];
        *((float4*)&sX[rr * KP + c4 * 4]) = v;
    }

    // stage W chunk 0
    float4 wreg[4];
    #pragma unroll
    for (int j = 0; j < 4; ++j) {
        int flat = tid + j * 256;          // 0..1023
        int kr = flat >> 5, c4 = flat & 31;
        wreg[j] = make_float4(0.f, 0.f, 0.f, 0.f);
        if (kr < K) wreg[j] = ((const float4*)&W[(size_t)kr * 128])[c4];
    }
    #pragma unroll
    for (int j = 0; j < 4; ++j) {
        int flat = tid + j * 256;
        int kr = flat >> 5, c4 = flat & 31;
        *((float4*)&sW[kr * 128 + c4 * 4]) = wreg[j];
    }
    __syncthreads();

    int cg = tid & 15;
    int r  = tid >> 4;
    float acc[4][8];
    #pragma unroll
    for (int i = 0; i < 4; ++i)
        #pragma unroll
        for (int j = 0; j < 8; ++j) acc[i][j] = 0.f;

    #pragma unroll
    for (int c = 0; c < NC; ++c) {
        const int kc = c * 32;
        const int klen = (K - kc < 32) ? (K - kc) : 32;
        // prefetch next W chunk into regs (overlaps with compute below)
        if (c + 1 < NC) {
            #pragma unroll
            for (int j = 0; j < 4; ++j) {
                int flat = tid + j * 256;
                int kr = (c + 1) * 32 + (flat >> 5);
                int c4 = flat & 31;
                wreg[j] = make_float4(0.f, 0.f, 0.f, 0.f);
                if (kr < K) wreg[j] = ((const float4*)&W[(size_t)kr * 128])[c4];
            }
        }
        // compute this chunk
        #pragma unroll
        for (int kk = 0; kk < klen; kk += 4) {
            float4 xv[4];
            #pragma unroll
            for (int i = 0; i < 4; ++i)
                xv[i] = *((const float4*)&sX[(r + 16 * i) * KP + kc + kk]);
            #pragma unroll
            for (int j = 0; j < 4; ++j) {
                float4 w0 = *((const float4*)&sW[(kk + j) * 128 + cg * 4]);
                float4 w1 = *((const float4*)&sW[(kk + j) * 128 + 64 + cg * 4]);
                #pragma unroll
                for (int i = 0; i < 4; ++i) {
                    float xs = (j == 0) ? xv[i].x : (j == 1) ? xv[i].y
                             : (j == 2) ? xv[i].z : xv[i].w;
                    acc[i][0] += xs * w0.x; acc[i][1] += xs * w0.y;
                    acc[i][2] += xs * w0.z; acc[i][3] += xs * w0.w;
                    acc[i][4] += xs * w1.x; acc[i][5] += xs * w1.y;
                    acc[i][6] += xs * w1.z; acc[i][7] += xs * w1.w;
                }
            }
        }
        if (c + 1 < NC) {
            __syncthreads();   // everyone done reading sW
            #pragma unroll
            for (int j = 0; j < 4; ++j) {
                int flat = tid + j * 256;
                int kr = flat >> 5, c4 = flat & 31;
                *((float4*)&sW[kr * 128 + c4 * 4]) = wreg[j];
            }
            __syncthreads();   // new chunk visible
        }
    }

    #pragma unroll
    for (int i = 0; i < 4; ++i) {
        int row = row0 + r + 16 * i;
        if (row < N) {
            float* y = &Y[(size_t)row * 128];
            *((float4*)&y[cg * 4])      = make_float4(acc[i][0], acc[i][1], acc[i][2], acc[i][3]);
            *((float4*)&y[64 + cg * 4]) = make_float4(acc[i][4], acc[i][5], acc[i][6], acc[i][7]);
        }
    }
}

// ---------------- BN(eval) scale/shift precompute ----------------

__global__ void scaleshift_kernel(const float* __restrict__ gamma, const float* __restrict__ beta,
                                  const float* __restrict__ rm, const float* __restrict__ rv,
                                  const float* __restrict__ b,
                                  float* __restrict__ scale, float* __restrict__ shift) {
    int j = threadIdx.x;   // 128 threads
    float sc = gamma[j] * rsqrtf(rv[j] + BN_EPS);
    scale[j] = sc;
    shift[j] = beta[j] + (b[j] - rm[j]) * sc;
}

// ---------------- fused aggregation: CSR gather + self-loop + BN + ReLU ----------------

__launch_bounds__(256)
__global__ void agg_kernel(const float* __restrict__ H, const int2* __restrict__ edges,
                           const int* __restrict__ rowptr, const float* __restrict__ dinv,
                           const float* __restrict__ scale, const float* __restrict__ shift,
                           float* __restrict__ out, int N) {
    int idx = blockIdx.x * blockDim.x + threadIdx.x;
    int node = idx >> 6, lane = idx & 63;
    if (node >= N) return;

    float d = dinv[node];
    float w0 = d * d;
    float2 h = ((const float2*)&H[(size_t)node * 128])[lane];
    float ax = h.x * w0, ay = h.y * w0;

    int beg = rowptr[node], end = rowptr[node + 1];
    for (int base = beg; base < end; base += 64) {
        int m = end - base; if (m > 64) m = 64;
        int2 pr = make_int2(0, 0);
        if (lane < m) pr = edges[base + lane];
        for (int j = 0; j < m; ++j) {
            int   s = __shfl(pr.x, j, 64);
            float w = __int_as_float(__shfl(pr.y, j, 64));
            float2 hs = ((const float2*)&H[(size_t)s * 128])[lane];
            ax += hs.x * w;
            ay += hs.y * w;
        }
    }

    float2 sc = ((const float2*)scale)[lane];
    float2 sh = ((const float2*)shift)[lane];
    float2 o;
    o.x = fmaxf(ax * sc.x + sh.x, 0.f);
    o.y = fmaxf(ay * sc.y + sh.y, 0.f);
    ((float2*)&out[(size_t)node * 128])[lane] = o;
}

// ---------------- pooling: graph boundaries + per-graph block reduction ----------------

__global__ void bounds_kernel(const int* __restrict__ batch, int* __restrict__ gstart,
                              int N, int G) {
    int i = blockIdx.x * blockDim.x + threadIdx.x;
    if (i >= N) return;
    int b = batch[i];
    int prev = (i == 0) ? -1 : batch[i - 1];
    for (int g = prev + 1; g <= b; ++g) gstart[g] = i;
    if (i == N - 1) {
        for (int g = b + 1; g <= G; ++g) gstart[g] = N;
    }
}

__launch_bounds__(256)
__global__ void pool2_kernel(const float* __restrict__ H, const int* __restrict__ gstart,
                             const float* __restrict__ Wout, const float* __restrict__ bout,
                             float* __restrict__ out, int G) {
    int g = blockIdx.x;
    int beg = gstart[g], end = gstart[g + 1];
    int t = threadIdx.x;
    int c = t & 127;
    int half = t >> 7;
    float acc = 0.f;
    for (int n = beg + half; n < end; n += 2)
        acc += H[(size_t)n * 128 + c];
    __shared__ float lds[256];
    lds[t] = acc * Wout[c];
    __syncthreads();
    if (t < 64) lds[t] = lds[t] + lds[t + 64] + lds[t + 128] + lds[t + 192];
    __syncthreads();
    if (t < 64) {
        float s = lds[t];
        #pragma unroll
        for (int off = 32; off > 0; off >>= 1) s += __shfl_down(s, off, 64);
        if (t == 0) {
            float cntf = (float)(end - beg);
            out[g] = s / fmaxf(cntf, 1.0f) + bout[0];
        }
    }
}

// ---------------- host launch ----------------

extern "C" void kernel_launch(void* const* d_in, const int* in_sizes, int n_in,
                              void* d_out, int out_size, void* d_ws, size_t ws_size,
                              hipStream_t stream) {
    const float* x     = (const float*)d_in[0];
    const int*   ei    = (const int*)d_in[1];
    const float* ew    = (const float*)d_in[2];
    const int*   batch = (const int*)d_in[3];
    const float* W0 = (const float*)d_in[4];
    const float* b0 = (const float*)d_in[5];
    const float* W1 = (const float*)d_in[6];
    const float* b1 = (const float*)d_in[7];
    const float* W2 = (const float*)d_in[8];
    const float* b2 = (const float*)d_in[9];
    const float* gamma = (const float*)d_in[10];
    const float* beta  = (const float*)d_in[11];
    const float* rmean = (const float*)d_in[12];
    const float* rvar  = (const float*)d_in[13];
    const float* Wout  = (const float*)d_in[14];
    const float* bout  = (const float*)d_in[15];

    const int E = in_sizes[2];
    const int N = in_sizes[3];
    const int D_IN = in_sizes[0] / N;   // 100
    const int G = out_size;

    const int* src = ei;
    const int* dst = ei + E;

    char* ws = (char*)d_ws;
    size_t off = 0;
    float* dinv  = (float*)(ws + off); off = align_up(off + (size_t)N * 4, 256);
    int* cntc    = (int*)(ws + off);   off = align_up(off + (size_t)N * 4, 256);
    int* excl    = (int*)(ws + off);   off = align_up(off + (size_t)N * 4, 256);
    int* rowptr  = (int*)(ws + off);   off = align_up(off + ((size_t)N + 1) * 4, 256);
    int* cursor  = (int*)(ws + off);   off = align_up(off + (size_t)N * 4, 256);
    int* bsum    = (int*)(ws + off);   off = align_up(off + 256 * 4, 256);
    int* gstart  = (int*)(ws + off);   off = align_up(off + ((size_t)G + 1) * 4, 256);
    int2* edges  = (int2*)(ws + off);  off = align_up(off + (size_t)E * 8, 256);
    float* buf0  = (float*)(ws + off); off = align_up(off + (size_t)N * 128 * 4, 256);
    float* buf1  = (float*)(ws + off); off = align_up(off + (size_t)N * 128 * 4, 256);
    float* scale = (float*)(ws + off); off = align_up(off + 128 * 4, 256);
    float* shift = (float*)(ws + off); off = align_up(off + 128 * 4, 256);
    (void)ws_size;

    hipMemsetAsync(dinv, 0, (size_t)N * 4, stream);
    hipMemsetAsync(cntc, 0, (size_t)N * 4, stream);

    const int tB = 256;
    hist_kernel<<<(E + tB - 1) / tB, tB, 0, stream>>>(dst, ew, dinv, cntc, E);
    dinv_kernel<<<(N + tB - 1) / tB, tB, 0, stream>>>(dinv, N);

    int nb = (N + 1023) / 1024;
    scan1_kernel<<<nb, 256, 0, stream>>>(cntc, excl, bsum, N);
    scan2_kernel<<<1, 256, 0, stream>>>(bsum, nb);
    scan3_kernel<<<(N + tB - 1) / tB, tB, 0, stream>>>(excl, bsum, rowptr, cursor, N, E);
    bucket_kernel<<<(E + tB - 1) / tB, tB, 0, stream>>>(src, dst, ew, dinv, cursor, edges, E);
    bounds_kernel<<<(N + tB - 1) / tB, tB, 0, stream>>>(batch, gstart, N, G);

    const float* Ws[3] = {W0, W1, W2};
    const float* bs[3] = {b0, b1, b2};

    long nthread_node = (long)N * 64;
    int blocks_node = (int)((nthread_node + tB - 1) / tB);
    int gemm_blocks = (N + 63) / 64;

    for (int l = 0; l < 3; ++l) {
        scaleshift_kernel<<<1, 128, 0, stream>>>(gamma + l * 128, beta + l * 128,
                                                 rmean + l * 128, rvar + l * 128,
                                                 bs[l], scale, shift);
        const float* in = (l == 0) ? x : buf1;
        if (l == 0) {
            if (D_IN == 100)
                gemm_kernel<100><<<gemm_blocks, 256, 0, stream>>>(in, Ws[l], buf0, N);
            else
                gemm_kernel<128><<<gemm_blocks, 256, 0, stream>>>(in, Ws[l], buf0, N);
        } else {
            gemm_kernel<128><<<gemm_blocks, 256, 0, stream>>>(in, Ws[l], buf0, N);
        }
        agg_kernel<<<blocks_node, tB, 0, stream>>>(buf0, edges, rowptr, dinv,
                                                   scale, shift, buf1, N);
    }

    pool2_kernel<<<G, 256, 0, stream>>>(buf1, gstart, Wout, bout, (float*)d_out, G);
}

// Round 5
// 625.754 us; speedup vs baseline: 9.9269x; 9.9269x over previous
//
#include <hip/hip_runtime.h>

#define BN_EPS 1e-5f

static inline size_t align_up(size_t x, size_t a) { return (x + a - 1) & ~(a - 1); }

// ---------------- histogram: float deg (sum ew) + int count per dst ----------------

__global__ void hist_kernel(const int* __restrict__ dst, const float* __restrict__ ew,
                            float* __restrict__ deg, int* __restrict__ cntc, int E) {
    int e = blockIdx.x * blockDim.x + threadIdx.x;
    if (e < E) {
        int d = dst[e];
        atomicAdd(&deg[d], ew[e]);
        atomicAdd(&cntc[d], 1);
    }
}

__global__ void dinv_kernel(float* deg, int N) {
    int i = blockIdx.x * blockDim.x + threadIdx.x;
    if (i < N) deg[i] = rsqrtf(deg[i] + 1.0f);   // +1 = self-loop weight
}

// ---------------- exclusive scan (3-phase) over cntc[N] -> rowptr/cursor ----------------

__global__ void scan1_kernel(const int* __restrict__ cnt, int* __restrict__ excl,
                             int* __restrict__ bsum, int N) {
    __shared__ int lds[256];
    int base = blockIdx.x * 1024;
    int t = threadIdx.x;
    int v[4]; int s = 0;
    #pragma unroll
    for (int j = 0; j < 4; ++j) {
        int idx = base + t * 4 + j;
        v[j] = (idx < N) ? cnt[idx] : 0;
        s += v[j];
    }
    lds[t] = s;
    __syncthreads();
    for (int off = 1; off < 256; off <<= 1) {
        int x = (t >= off) ? lds[t - off] : 0;
        __syncthreads();
        lds[t] += x;
        __syncthreads();
    }
    int run = lds[t] - s;
    #pragma unroll
    for (int j = 0; j < 4; ++j) {
        int idx = base + t * 4 + j;
        if (idx < N) excl[idx] = run;
        run += v[j];
    }
    if (t == 255) bsum[blockIdx.x] = lds[255];
}

__global__ void scan2_kernel(int* __restrict__ bsum, int nb) {
    __shared__ int lds[256];
    int t = threadIdx.x;
    int v = (t < nb) ? bsum[t] : 0;
    lds[t] = v;
    __syncthreads();
    for (int off = 1; off < 256; off <<= 1) {
        int x = (t >= off) ? lds[t - off] : 0;
        __syncthreads();
        lds[t] += x;
        __syncthreads();
    }
    if (t < nb) bsum[t] = lds[t] - v;
}

__global__ void scan3_kernel(const int* __restrict__ excl, const int* __restrict__ bsum,
                             int* __restrict__ rowptr, int* __restrict__ cursor, int N, int E) {
    int idx = blockIdx.x * blockDim.x + threadIdx.x;
    if (idx < N) {
        int v = excl[idx] + bsum[idx >> 10];
        rowptr[idx] = v;
        cursor[idx] = v;
    }
    if (idx == 0) rowptr[N] = E;
}

// ---------------- bucket edges by dst: edges[pos] = (src, norm) ----------------

__global__ void bucket_kernel(const int* __restrict__ src, const int* __restrict__ dst,
                              const float* __restrict__ ew, const float* __restrict__ dinv,
                              int* __restrict__ cursor, int2* __restrict__ edges, int E) {
    int e = blockIdx.x * blockDim.x + threadIdx.x;
    if (e >= E) return;
    int s = src[e], d = dst[e];
    float nrm = dinv[s] * ew[e] * dinv[d];
    int pos = atomicAdd(&cursor[d], 1);
    edges[pos] = make_int2(s, __float_as_int(nrm));
}

// ---------------- fp32 GEMM: Y[N x 128] = X[N x K] @ W[K x 128] ----------------
// 64 rows/block, 256 threads. Thread (cg=tid&15, r=tid>>4) computes rows
// {r, r+16, r+32, r+48} x cols {cg*4..+3, 64+cg*4..+3}.
// W col split cg*4 / 64+cg*4 -> 16 b128 addrs cover 32 banks 2-way (free, m136).
// sX row stride K+4 -> row addrs land on distinct banks.
// W staged per 32-k chunk (16 KB), NO outer unroll, NO persistent prefetch regs
// (R3 post-mortem: unroll+prefetch -> 256 VGPR cap -> scratch spills -> 2.6 GB fetch).
// LDS ~49 KB -> 3 blocks/CU; launch_bounds(256,3) caps VGPR alloc ~168.

template<int K>
__launch_bounds__(256, 3)
__global__ void gemm_kernel(const float* __restrict__ X, const float* __restrict__ W,
                            float* __restrict__ Y, int N) {
    constexpr int KP = K + 4;            // padded sX row stride
    constexpr int K4 = K / 4;
    constexpr int NC_FULL = K / 32;      // full 32-k chunks
    constexpr int TAIL = K - NC_FULL * 32;
    __shared__ float sX[64 * KP];
    __shared__ float sW[32 * 128];

    int row0 = blockIdx.x * 64;
    int tid = threadIdx.x;

    // stage X tile: 64 rows x K floats (coalesced float4)
    for (int i = tid; i < 64 * K4; i += 256) {
        int rr = i / K4, c4 = i - rr * K4;
        int row = row0 + rr;
        float4 v = make_float4(0.f, 0.f, 0.f, 0.f);
        if (row < N) v = ((const float4*)&X[(size_t)row * K])[c4];
        *((float4*)&sX[rr * KP + c4 * 4]) = v;
    }

    int cg = tid & 15;
    int r  = tid >> 4;
    float acc[4][8];
    #pragma unroll
    for (int i = 0; i < 4; ++i)
        #pragma unroll
        for (int j = 0; j < 8; ++j) acc[i][j] = 0.f;

    #pragma unroll 1
    for (int c = 0; c < NC_FULL; ++c) {
        const int kc = c * 32;
        float4 wr[4];
        #pragma unroll
        for (int j = 0; j < 4; ++j) {
            int flat = j * 256 + tid;
            int kr = kc + (flat >> 5);
            wr[j] = ((const float4*)&W[(size_t)kr * 128])[flat & 31];
        }
        __syncthreads();   // all waves done reading previous sW chunk (and sX staged, c==0)
        #pragma unroll
        for (int j = 0; j < 4; ++j) {
            int flat = j * 256 + tid;
            *((float4*)&sW[(flat >> 5) * 128 + (flat & 31) * 4]) = wr[j];
        }
        __syncthreads();

        #pragma unroll
        for (int kk = 0; kk < 32; kk += 4) {
            float4 xv[4];
            #pragma unroll
            for (int i = 0; i < 4; ++i)
                xv[i] = *((const float4*)&sX[(r + 16 * i) * KP + kc + kk]);
            #pragma unroll
            for (int j = 0; j < 4; ++j) {
                float4 w0 = *((const float4*)&sW[(kk + j) * 128 + cg * 4]);
                float4 w1 = *((const float4*)&sW[(kk + j) * 128 + 64 + cg * 4]);
                #pragma unroll
                for (int i = 0; i < 4; ++i) {
                    float xs = (j == 0) ? xv[i].x : (j == 1) ? xv[i].y
                             : (j == 2) ? xv[i].z : xv[i].w;
                    acc[i][0] += xs * w0.x; acc[i][1] += xs * w0.y;
                    acc[i][2] += xs * w0.z; acc[i][3] += xs * w0.w;
                    acc[i][4] += xs * w1.x; acc[i][5] += xs * w1.y;
                    acc[i][6] += xs * w1.z; acc[i][7] += xs * w1.w;
                }
            }
        }
    }

    if (TAIL > 0) {
        const int kc = NC_FULL * 32;
        float4 wt = make_float4(0.f, 0.f, 0.f, 0.f);
        if (tid < TAIL * 32) {
            int kr = kc + (tid >> 5);
            wt = ((const float4*)&W[(size_t)kr * 128])[tid & 31];
        }
        __syncthreads();
        if (tid < TAIL * 32)
            *((float4*)&sW[(tid >> 5) * 128 + (tid & 31) * 4]) = wt;
        __syncthreads();
        #pragma unroll
        for (int kk = 0; kk < TAIL; kk += 4) {
            float4 xv[4];
            #pragma unroll
            for (int i = 0; i < 4; ++i)
                xv[i] = *((const float4*)&sX[(r + 16 * i) * KP + kc + kk]);
            #pragma unroll
            for (int j = 0; j < 4; ++j) {
                float4 w0 = *((const float4*)&sW[(kk + j) * 128 + cg * 4]);
                float4 w1 = *((const float4*)&sW[(kk + j) * 128 + 64 + cg * 4]);
                #pragma unroll
                for (int i = 0; i < 4; ++i) {
                    float xs = (j == 0) ? xv[i].x : (j == 1) ? xv[i].y
                             : (j == 2) ? xv[i].z : xv[i].w;
                    acc[i][0] += xs * w0.x; acc[i][1] += xs * w0.y;
                    acc[i][2] += xs * w0.z; acc[i][3] += xs * w0.w;
                    acc[i][4] += xs * w1.x; acc[i][5] += xs * w1.y;
                    acc[i][6] += xs * w1.z; acc[i][7] += xs * w1.w;
                }
            }
        }
    }

    #pragma unroll
    for (int i = 0; i < 4; ++i) {
        int row = row0 + r + 16 * i;
        if (row < N) {
            float* y = &Y[(size_t)row * 128];
            *((float4*)&y[cg * 4])      = make_float4(acc[i][0], acc[i][1], acc[i][2], acc[i][3]);
            *((float4*)&y[64 + cg * 4]) = make_float4(acc[i][4], acc[i][5], acc[i][6], acc[i][7]);
        }
    }
}

// ---------------- BN(eval) scale/shift precompute ----------------

__global__ void scaleshift_kernel(const float* __restrict__ gamma, const float* __restrict__ beta,
                                  const float* __restrict__ rm, const float* __restrict__ rv,
                                  const float* __restrict__ b,
                                  float* __restrict__ scale, float* __restrict__ shift) {
    int j = threadIdx.x;   // 128 threads
    float sc = gamma[j] * rsqrtf(rv[j] + BN_EPS);
    scale[j] = sc;
    shift[j] = beta[j] + (b[j] - rm[j]) * sc;
}

// ---------------- fused aggregation: CSR gather + self-loop + BN + ReLU ----------------

__launch_bounds__(256)
__global__ void agg_kernel(const float* __restrict__ H, const int2* __restrict__ edges,
                           const int* __restrict__ rowptr, const float* __restrict__ dinv,
                           const float* __restrict__ scale, const float* __restrict__ shift,
                           float* __restrict__ out, int N) {
    int idx = blockIdx.x * blockDim.x + threadIdx.x;
    int node = idx >> 6, lane = idx & 63;
    if (node >= N) return;

    float d = dinv[node];
    float w0 = d * d;
    float2 h = ((const float2*)&H[(size_t)node * 128])[lane];
    float ax = h.x * w0, ay = h.y * w0;

    int beg = rowptr[node], end = rowptr[node + 1];
    for (int base = beg; base < end; base += 64) {
        int m = end - base; if (m > 64) m = 64;
        int2 pr = make_int2(0, 0);
        if (lane < m) pr = edges[base + lane];
        for (int j = 0; j < m; ++j) {
            int   s = __shfl(pr.x, j, 64);
            float w = __int_as_float(__shfl(pr.y, j, 64));
            float2 hs = ((const float2*)&H[(size_t)s * 128])[lane];
            ax += hs.x * w;
            ay += hs.y * w;
        }
    }

    float2 sc = ((const float2*)scale)[lane];
    float2 sh = ((const float2*)shift)[lane];
    float2 o;
    o.x = fmaxf(ax * sc.x + sh.x, 0.f);
    o.y = fmaxf(ay * sc.y + sh.y, 0.f);
    ((float2*)&out[(size_t)node * 128])[lane] = o;
}

// ---------------- pooling: graph boundaries + per-graph block reduction ----------------

__global__ void bounds_kernel(const int* __restrict__ batch, int* __restrict__ gstart,
                              int N, int G) {
    int i = blockIdx.x * blockDim.x + threadIdx.x;
    if (i >= N) return;
    int b = batch[i];
    int prev = (i == 0) ? -1 : batch[i - 1];
    for (int g = prev + 1; g <= b; ++g) gstart[g] = i;
    if (i == N - 1) {
        for (int g = b + 1; g <= G; ++g) gstart[g] = N;
    }
}

__launch_bounds__(256)
__global__ void pool2_kernel(const float* __restrict__ H, const int* __restrict__ gstart,
                             const float* __restrict__ Wout, const float* __restrict__ bout,
                             float* __restrict__ out, int G) {
    int g = blockIdx.x;
    int beg = gstart[g], end = gstart[g + 1];
    int t = threadIdx.x;
    int c = t & 127;
    int half = t >> 7;
    float acc = 0.f;
    for (int n = beg + half; n < end; n += 2)
        acc += H[(size_t)n * 128 + c];
    __shared__ float lds[256];
    lds[t] = acc * Wout[c];
    __syncthreads();
    if (t < 64) lds[t] = lds[t] + lds[t + 64] + lds[t + 128] + lds[t + 192];
    __syncthreads();
    if (t < 64) {
        float s = lds[t];
        #pragma unroll
        for (int off = 32; off > 0; off >>= 1) s += __shfl_down(s, off, 64);
        if (t == 0) {
            float cntf = (float)(end - beg);
            out[g] = s / fmaxf(cntf, 1.0f) + bout[0];
        }
    }
}

// ---------------- host launch ----------------

extern "C" void kernel_launch(void* const* d_in, const int* in_sizes, int n_in,
                              void* d_out, int out_size, void* d_ws, size_t ws_size,
                              hipStream_t stream) {
    const float* x     = (const float*)d_in[0];
    const int*   ei    = (const int*)d_in[1];
    const float* ew    = (const float*)d_in[2];
    const int*   batch = (const int*)d_in[3];
    const float* W0 = (const float*)d_in[4];
    const float* b0 = (const float*)d_in[5];
    const float* W1 = (const float*)d_in[6];
    const float* b1 = (const float*)d_in[7];
    const float* W2 = (const float*)d_in[8];
    const float* b2 = (const float*)d_in[9];
    const float* gamma = (const float*)d_in[10];
    const float* beta  = (const float*)d_in[11];
    const float* rmean = (const float*)d_in[12];
    const float* rvar  = (const float*)d_in[13];
    const float* Wout  = (const float*)d_in[14];
    const float* bout  = (const float*)d_in[15];

    const int E = in_sizes[2];
    const int N = in_sizes[3];
    const int D_IN = in_sizes[0] / N;   // 100
    const int G = out_size;

    const int* src = ei;
    const int* dst = ei + E;

    char* ws = (char*)d_ws;
    size_t off = 0;
    float* dinv  = (float*)(ws + off); off = align_up(off + (size_t)N * 4, 256);
    int* cntc    = (int*)(ws + off);   off = align_up(off + (size_t)N * 4, 256);
    int* excl    = (int*)(ws + off);   off = align_up(off + (size_t)N * 4, 256);
    int* rowptr  = (int*)(ws + off);   off = align_up(off + ((size_t)N + 1) * 4, 256);
    int* cursor  = (int*)(ws + off);   off = align_up(off + (size_t)N * 4, 256);
    int* bsum    = (int*)(ws + off);   off = align_up(off + 256 * 4, 256);
    int* gstart  = (int*)(ws + off);   off = align_up(off + ((size_t)G + 1) * 4, 256);
    int2* edges  = (int2*)(ws + off);  off = align_up(off + (size_t)E * 8, 256);
    float* buf0  = (float*)(ws + off); off = align_up(off + (size_t)N * 128 * 4, 256);
    float* buf1  = (float*)(ws + off); off = align_up(off + (size_t)N * 128 * 4, 256);
    float* scale = (float*)(ws + off); off = align_up(off + 128 * 4, 256);
    float* shift = (float*)(ws + off); off = align_up(off + 128 * 4, 256);
    (void)ws_size;

    hipMemsetAsync(dinv, 0, (size_t)N * 4, stream);
    hipMemsetAsync(cntc, 0, (size_t)N * 4, stream);

    const int tB = 256;
    hist_kernel<<<(E + tB - 1) / tB, tB, 0, stream>>>(dst, ew, dinv, cntc, E);
    dinv_kernel<<<(N + tB - 1) / tB, tB, 0, stream>>>(dinv, N);

    int nb = (N + 1023) / 1024;
    scan1_kernel<<<nb, 256, 0, stream>>>(cntc, excl, bsum, N);
    scan2_kernel<<<1, 256, 0, stream>>>(bsum, nb);
    scan3_kernel<<<(N + tB - 1) / tB, tB, 0, stream>>>(excl, bsum, rowptr, cursor, N, E);
    bucket_kernel<<<(E + tB - 1) / tB, tB, 0, stream>>>(src, dst, ew, dinv, cursor, edges, E);
    bounds_kernel<<<(N + tB - 1) / tB, tB, 0, stream>>>(batch, gstart, N, G);

    const float* Ws[3] = {W0, W1, W2};
    const float* bs[3] = {b0, b1, b2};

    long nthread_node = (long)N * 64;
    int blocks_node = (int)((nthread_node + tB - 1) / tB);
    int gemm_blocks = (N + 63) / 64;

    for (int l = 0; l < 3; ++l) {
        scaleshift_kernel<<<1, 128, 0, stream>>>(gamma + l * 128, beta + l * 128,
                                                 rmean + l * 128, rvar + l * 128,
                                                 bs[l], scale, shift);
        const float* in = (l == 0) ? x : buf1;
        if (l == 0) {
            if (D_IN == 100)
                gemm_kernel<100><<<gemm_blocks, 256, 0, stream>>>(in, Ws[l], buf0, N);
            else
                gemm_kernel<128><<<gemm_blocks, 256, 0, stream>>>(in, Ws[l], buf0, N);
        } else {
            gemm_kernel<128><<<gemm_blocks, 256, 0, stream>>>(in, Ws[l], buf0, N);
        }
        agg_kernel<<<blocks_node, tB, 0, stream>>>(buf0, edges, rowptr, dinv,
                                                   scale, shift, buf1, N);
    }

    pool2_kernel<<<G, 256, 0, stream>>>(buf1, gstart, Wout, bout, (float*)d_out, G);
}

// Round 6
// 608.399 us; speedup vs baseline: 10.2101x; 1.0285x over previous
//
#include <hip/hip_runtime.h>

#define BN_EPS 1e-5f

static inline size_t align_up(size_t x, size_t a) { return (x + a - 1) & ~(a - 1); }

// ---------------- histogram: float deg (sum ew) + int count per dst ----------------

__global__ void hist_kernel(const int* __restrict__ dst, const float* __restrict__ ew,
                            float* __restrict__ deg, int* __restrict__ cntc, int E) {
    int e = blockIdx.x * blockDim.x + threadIdx.x;
    if (e < E) {
        int d = dst[e];
        atomicAdd(&deg[d], ew[e]);
        atomicAdd(&cntc[d], 1);
    }
}

__global__ void dinv_kernel(float* deg, int N) {
    int i = blockIdx.x * blockDim.x + threadIdx.x;
    if (i < N) deg[i] = rsqrtf(deg[i] + 1.0f);   // +1 = self-loop weight
}

// ---------------- exclusive scan (3-phase) over cntc[N] -> rowptr/cursor ----------------

__global__ void scan1_kernel(const int* __restrict__ cnt, int* __restrict__ excl,
                             int* __restrict__ bsum, int N) {
    __shared__ int lds[256];
    int base = blockIdx.x * 1024;
    int t = threadIdx.x;
    int v[4]; int s = 0;
    #pragma unroll
    for (int j = 0; j < 4; ++j) {
        int idx = base + t * 4 + j;
        v[j] = (idx < N) ? cnt[idx] : 0;
        s += v[j];
    }
    lds[t] = s;
    __syncthreads();
    for (int off = 1; off < 256; off <<= 1) {
        int x = (t >= off) ? lds[t - off] : 0;
        __syncthreads();
        lds[t] += x;
        __syncthreads();
    }
    int run = lds[t] - s;
    #pragma unroll
    for (int j = 0; j < 4; ++j) {
        int idx = base + t * 4 + j;
        if (idx < N) excl[idx] = run;
        run += v[j];
    }
    if (t == 255) bsum[blockIdx.x] = lds[255];
}

__global__ void scan2_kernel(int* __restrict__ bsum, int nb) {
    __shared__ int lds[256];
    int t = threadIdx.x;
    int v = (t < nb) ? bsum[t] : 0;
    lds[t] = v;
    __syncthreads();
    for (int off = 1; off < 256; off <<= 1) {
        int x = (t >= off) ? lds[t - off] : 0;
        __syncthreads();
        lds[t] += x;
        __syncthreads();
    }
    if (t < nb) bsum[t] = lds[t] - v;
}

__global__ void scan3_kernel(const int* __restrict__ excl, const int* __restrict__ bsum,
                             int* __restrict__ rowptr, int* __restrict__ cursor, int N, int E) {
    int idx = blockIdx.x * blockDim.x + threadIdx.x;
    if (idx < N) {
        int v = excl[idx] + bsum[idx >> 10];
        rowptr[idx] = v;
        cursor[idx] = v;
    }
    if (idx == 0) rowptr[N] = E;
}

// ---------------- bucket edges by dst: edges[pos] = (src, norm) ----------------

__global__ void bucket_kernel(const int* __restrict__ src, const int* __restrict__ dst,
                              const float* __restrict__ ew, const float* __restrict__ dinv,
                              int* __restrict__ cursor, int2* __restrict__ edges, int E) {
    int e = blockIdx.x * blockDim.x + threadIdx.x;
    if (e >= E) return;
    int s = src[e], d = dst[e];
    float nrm = dinv[s] * ew[e] * dinv[d];
    int pos = atomicAdd(&cursor[d], 1);
    edges[pos] = make_int2(s, __float_as_int(nrm));
}

// ---------------- fp32 GEMM: Y[N x 128] = X[N x K] @ W[K x 128] ----------------
// 128 rows/block, 256 threads. Thread (cg=tid&15, r=tid>>4) computes rows
// {r+16i, i=0..7} x cols {cg*4..+3, 64+cg*4..+3} (8x8 = 64 acc).
// W fully staged in LDS (K*512 B, ONE barrier); X read直接 from global: 16 lanes
// sharing a row load the same address -> HW broadcast, k-sequential sweep stays
// L1-resident. Per kk-step: 8 b128 LDS per 256 FMAs -> VALU-bound (~75% ceiling)
// vs R4's 96 B/128 FMA LDS-bound shape (47% ceiling, observed 33%).
// unroll 1 + launch_bounds(256,2): R3 post-mortem (spills at 256 VGPR cap).

template<int K>
__launch_bounds__(256, 2)
__global__ void gemm_kernel(const float* __restrict__ X, const float* __restrict__ W,
                            float* __restrict__ Y, int N) {
    __shared__ float sW[K * 128];
    int tid = threadIdx.x;
    for (int i = tid; i < K * 32; i += 256)
        ((float4*)sW)[i] = ((const float4*)W)[i];
    __syncthreads();

    int row0 = blockIdx.x * 128;
    int cg = tid & 15;
    int r  = tid >> 4;

    // clamped row pointers: OOB rows read row N-1 (valid, finite); stores guarded.
    const float* xp[8];
    #pragma unroll
    for (int i = 0; i < 8; ++i) {
        int row = row0 + r + 16 * i;
        if (row > N - 1) row = N - 1;
        xp[i] = &X[(size_t)row * K];
    }

    float acc[8][8];
    #pragma unroll
    for (int i = 0; i < 8; ++i)
        #pragma unroll
        for (int j = 0; j < 8; ++j) acc[i][j] = 0.f;

    #pragma unroll 1
    for (int kk = 0; kk < K; kk += 4) {
        float4 xv[8];
        #pragma unroll
        for (int i = 0; i < 8; ++i)
            xv[i] = *((const float4*)(xp[i] + kk));
        #pragma unroll
        for (int j = 0; j < 4; ++j) {
            float4 w0 = *((const float4*)&sW[(kk + j) * 128 + cg * 4]);
            float4 w1 = *((const float4*)&sW[(kk + j) * 128 + 64 + cg * 4]);
            #pragma unroll
            for (int i = 0; i < 8; ++i) {
                float xs = (j == 0) ? xv[i].x : (j == 1) ? xv[i].y
                         : (j == 2) ? xv[i].z : xv[i].w;
                acc[i][0] += xs * w0.x; acc[i][1] += xs * w0.y;
                acc[i][2] += xs * w0.z; acc[i][3] += xs * w0.w;
                acc[i][4] += xs * w1.x; acc[i][5] += xs * w1.y;
                acc[i][6] += xs * w1.z; acc[i][7] += xs * w1.w;
            }
        }
    }

    #pragma unroll
    for (int i = 0; i < 8; ++i) {
        int row = row0 + r + 16 * i;
        if (row < N) {
            float* y = &Y[(size_t)row * 128];
            *((float4*)&y[cg * 4])      = make_float4(acc[i][0], acc[i][1], acc[i][2], acc[i][3]);
            *((float4*)&y[64 + cg * 4]) = make_float4(acc[i][4], acc[i][5], acc[i][6], acc[i][7]);
        }
    }
}

// ---------------- BN(eval) scale/shift precompute ----------------

__global__ void scaleshift_kernel(const float* __restrict__ gamma, const float* __restrict__ beta,
                                  const float* __restrict__ rm, const float* __restrict__ rv,
                                  const float* __restrict__ b,
                                  float* __restrict__ scale, float* __restrict__ shift) {
    int j = threadIdx.x;   // 128 threads
    float sc = gamma[j] * rsqrtf(rv[j] + BN_EPS);
    scale[j] = sc;
    shift[j] = beta[j] + (b[j] - rm[j]) * sc;
}

// ---------------- fused aggregation: CSR gather + self-loop + BN + ReLU ----------------
// one wave per dst node; edge (src,norm) broadcast via readlane (wave-uniform j)
// -> zero LDS-pipe ops in the inner loop (was 2 ds_bpermute/edge via __shfl).

__launch_bounds__(256)
__global__ void agg_kernel(const float* __restrict__ H, const int2* __restrict__ edges,
                           const int* __restrict__ rowptr, const float* __restrict__ dinv,
                           const float* __restrict__ scale, const float* __restrict__ shift,
                           float* __restrict__ out, int N) {
    int idx = blockIdx.x * blockDim.x + threadIdx.x;
    int node = idx >> 6, lane = idx & 63;
    if (node >= N) return;

    float d = dinv[node];
    float w0 = d * d;
    float2 h = ((const float2*)&H[(size_t)node * 128])[lane];
    float ax = h.x * w0, ay = h.y * w0;

    int beg = rowptr[node], end = rowptr[node + 1];
    for (int base = beg; base < end; base += 64) {
        int m = end - base; if (m > 64) m = 64;
        int2 pr = make_int2(0, 0);
        if (lane < m) pr = edges[base + lane];
        for (int j = 0; j < m; ++j) {
            int   s = __builtin_amdgcn_readlane(pr.x, j);
            float w = __int_as_float(__builtin_amdgcn_readlane(pr.y, j));
            float2 hs = ((const float2*)&H[(size_t)s * 128])[lane];
            ax += hs.x * w;
            ay += hs.y * w;
        }
    }

    float2 sc = ((const float2*)scale)[lane];
    float2 sh = ((const float2*)shift)[lane];
    float2 o;
    o.x = fmaxf(ax * sc.x + sh.x, 0.f);
    o.y = fmaxf(ay * sc.y + sh.y, 0.f);
    ((float2*)&out[(size_t)node * 128])[lane] = o;
}

// ---------------- pooling: graph boundaries + per-graph block reduction ----------------

__global__ void bounds_kernel(const int* __restrict__ batch, int* __restrict__ gstart,
                              int N, int G) {
    int i = blockIdx.x * blockDim.x + threadIdx.x;
    if (i >= N) return;
    int b = batch[i];
    int prev = (i == 0) ? -1 : batch[i - 1];
    for (int g = prev + 1; g <= b; ++g) gstart[g] = i;
    if (i == N - 1) {
        for (int g = b + 1; g <= G; ++g) gstart[g] = N;
    }
}

__launch_bounds__(256)
__global__ void pool2_kernel(const float* __restrict__ H, const int* __restrict__ gstart,
                             const float* __restrict__ Wout, const float* __restrict__ bout,
                             float* __restrict__ out, int G) {
    int g = blockIdx.x;
    int beg = gstart[g], end = gstart[g + 1];
    int t = threadIdx.x;
    int c = t & 127;
    int half = t >> 7;
    float acc = 0.f;
    for (int n = beg + half; n < end; n += 2)
        acc += H[(size_t)n * 128 + c];
    __shared__ float lds[256];
    lds[t] = acc * Wout[c];
    __syncthreads();
    if (t < 64) lds[t] = lds[t] + lds[t + 64] + lds[t + 128] + lds[t + 192];
    __syncthreads();
    if (t < 64) {
        float s = lds[t];
        #pragma unroll
        for (int off = 32; off > 0; off >>= 1) s += __shfl_down(s, off, 64);
        if (t == 0) {
            float cntf = (float)(end - beg);
            out[g] = s / fmaxf(cntf, 1.0f) + bout[0];
        }
    }
}

// ---------------- host launch ----------------

extern "C" void kernel_launch(void* const* d_in, const int* in_sizes, int n_in,
                              void* d_out, int out_size, void* d_ws, size_t ws_size,
                              hipStream_t stream) {
    const float* x     = (const float*)d_in[0];
    const int*   ei    = (const int*)d_in[1];
    const float* ew    = (const float*)d_in[2];
    const int*   batch = (const int*)d_in[3];
    const float* W0 = (const float*)d_in[4];
    const float* b0 = (const float*)d_in[5];
    const float* W1 = (const float*)d_in[6];
    const float* b1 = (const float*)d_in[7];
    const float* W2 = (const float*)d_in[8];
    const float* b2 = (const float*)d_in[9];
    const float* gamma = (const float*)d_in[10];
    const float* beta  = (const float*)d_in[11];
    const float* rmean = (const float*)d_in[12];
    const float* rvar  = (const float*)d_in[13];
    const float* Wout  = (const float*)d_in[14];
    const float* bout  = (const float*)d_in[15];

    const int E = in_sizes[2];
    const int N = in_sizes[3];
    const int D_IN = in_sizes[0] / N;   // 100
    const int G = out_size;

    const int* src = ei;
    const int* dst = ei + E;

    char* ws = (char*)d_ws;
    size_t off = 0;
    float* dinv  = (float*)(ws + off); off = align_up(off + (size_t)N * 4, 256);
    int* cntc    = (int*)(ws + off);   off = align_up(off + (size_t)N * 4, 256);
    int* excl    = (int*)(ws + off);   off = align_up(off + (size_t)N * 4, 256);
    int* rowptr  = (int*)(ws + off);   off = align_up(off + ((size_t)N + 1) * 4, 256);
    int* cursor  = (int*)(ws + off);   off = align_up(off + (size_t)N * 4, 256);
    int* bsum    = (int*)(ws + off);   off = align_up(off + 256 * 4, 256);
    int* gstart  = (int*)(ws + off);   off = align_up(off + ((size_t)G + 1) * 4, 256);
    int2* edges  = (int2*)(ws + off);  off = align_up(off + (size_t)E * 8, 256);
    float* buf0  = (float*)(ws + off); off = align_up(off + (size_t)N * 128 * 4, 256);
    float* buf1  = (float*)(ws + off); off = align_up(off + (size_t)N * 128 * 4, 256);
    float* scale = (float*)(ws + off); off = align_up(off + 128 * 4, 256);
    float* shift = (float*)(ws + off); off = align_up(off + 128 * 4, 256);
    (void)ws_size;

    hipMemsetAsync(dinv, 0, (size_t)N * 4, stream);
    hipMemsetAsync(cntc, 0, (size_t)N * 4, stream);

    const int tB = 256;
    hist_kernel<<<(E + tB - 1) / tB, tB, 0, stream>>>(dst, ew, dinv, cntc, E);
    dinv_kernel<<<(N + tB - 1) / tB, tB, 0, stream>>>(dinv, N);

    int nb = (N + 1023) / 1024;
    scan1_kernel<<<nb, 256, 0, stream>>>(cntc, excl, bsum, N);
    scan2_kernel<<<1, 256, 0, stream>>>(bsum, nb);
    scan3_kernel<<<(N + tB - 1) / tB, tB, 0, stream>>>(excl, bsum, rowptr, cursor, N, E);
    bucket_kernel<<<(E + tB - 1) / tB, tB, 0, stream>>>(src, dst, ew, dinv, cursor, edges, E);
    bounds_kernel<<<(N + tB - 1) / tB, tB, 0, stream>>>(batch, gstart, N, G);

    const float* Ws[3] = {W0, W1, W2};
    const float* bs[3] = {b0, b1, b2};

    long nthread_node = (long)N * 64;
    int blocks_node = (int)((nthread_node + tB - 1) / tB);
    int gemm_blocks = (N + 127) / 128;

    for (int l = 0; l < 3; ++l) {
        scaleshift_kernel<<<1, 128, 0, stream>>>(gamma + l * 128, beta + l * 128,
                                                 rmean + l * 128, rvar + l * 128,
                                                 bs[l], scale, shift);
        const float* in = (l == 0) ? x : buf1;
        if (l == 0) {
            if (D_IN == 100)
                gemm_kernel<100><<<gemm_blocks, 256, 0, stream>>>(in, Ws[l], buf0, N);
            else
                gemm_kernel<128><<<gemm_blocks, 256, 0, stream>>>(in, Ws[l], buf0, N);
        } else {
            gemm_kernel<128><<<gemm_blocks, 256, 0, stream>>>(in, Ws[l], buf0, N);
        }
        agg_kernel<<<blocks_node, tB, 0, stream>>>(buf0, edges, rowptr, dinv,
                                                   scale, shift, buf1, N);
    }

    pool2_kernel<<<G, 256, 0, stream>>>(buf1, gstart, Wout, bout, (float*)d_out, G);
}